// Round 1
// baseline (1683.719 us; speedup 1.0000x reference)
//
#include <hip/hip_runtime.h>
#include <hip/hip_bf16.h>

#define DIM 128
#define G4 512      // 4*DIM
#define NL 4
#define VOCAB 32000
#define BB 32
#define SS 256
#define ROWS (BB*SS)   // 8192

typedef __attribute__((ext_vector_type(8))) short short8;
typedef __attribute__((ext_vector_type(4))) float f32x4;

__device__ __forceinline__ float fexp_(float x){ return __builtin_amdgcn_exp2f(x * 1.44269504088896f); }
__device__ __forceinline__ float frcp_(float x){ return __builtin_amdgcn_rcpf(x); }
__device__ __forceinline__ float sigm_(float x){ return frcp_(1.f + fexp_(-x)); }
__device__ __forceinline__ float tanh_(float x){
    float ax = fabsf(x);
    float e = fexp_(-2.f * ax);
    float t = (1.f - e) * frcp_(1.f + e);
    return x < 0.f ? -t : t;
}

// ---------------- K1: embedding gather ----------------
__global__ void k_embed(const int* __restrict__ x, const float* __restrict__ emb,
                        float* __restrict__ hseq){
    int i = blockIdx.x * blockDim.x + threadIdx.x;   // float4 index, 262144 total
    int row = i >> 5;      // 32 float4 per row of 128
    int d4  = i & 31;
    int tok = x[row];
    ((float4*)hseq)[i] = ((const float4*)emb)[tok * 32 + d4];
}

// ---------------- K2: xW = hseq @ Wih^T + bih + bhh ----------------
// grid 256 blocks x 512 threads; block handles 32 rows, thread g holds Wih row g in VGPRs.
__global__ __launch_bounds__(512, 2) void k_xw(const float* __restrict__ hseq,
                                               const float* __restrict__ Wih,
                                               const float* __restrict__ bih,
                                               const float* __restrict__ bhh,
                                               float* __restrict__ xw){
    __shared__ float hs[32 * DIM];
    int g = threadIdx.x;
    int r0 = blockIdx.x * 32;
    { // stage 32 rows (contiguous 16 KB), coalesced
        const float4* src = (const float4*)(hseq + (size_t)r0 * DIM);
        float4* dst = (float4*)hs;
        for (int j = g; j < 32 * 32; j += 512) dst[j] = src[j];
    }
    float4 w[32];
    const float4* wr = (const float4*)(Wih + (size_t)g * DIM);
#pragma unroll
    for (int j = 0; j < 32; ++j) w[j] = wr[j];
    float bias = bih[g] + bhh[g];
    __syncthreads();
    for (int r = 0; r < 32; ++r){
        const float4* h4 = (const float4*)(hs + r * DIM);
        float acc = bias;
#pragma unroll
        for (int j = 0; j < 32; ++j){
            float4 hv = h4[j];  // uniform address -> LDS broadcast
            acc = fmaf(hv.x, w[j].x, fmaf(hv.y, w[j].y, fmaf(hv.z, w[j].z, fmaf(hv.w, w[j].w, acc))));
        }
        xw[(size_t)(r0 + r) * G4 + g] = acc;
    }
}

// ---------------- K3: LSTM scan for one layer ----------------
// grid 32 blocks (one per batch) x 512 threads; thread g holds Whh row g in VGPRs.
__global__ __launch_bounds__(512, 2) void k_scan(const float* __restrict__ xw,
                                                 const float* __restrict__ Whh,
                                                 float* __restrict__ hseq){
    __shared__ float hbuf[2][DIM];
    __shared__ float gates[G4];
    int g = threadIdx.x;
    int b = blockIdx.x;
    float4 w[32];
    const float4* wr = (const float4*)(Whh + (size_t)g * DIM);
#pragma unroll
    for (int j = 0; j < 32; ++j) w[j] = wr[j];
    float c = 0.f;
    if (g < DIM) hbuf[0][g] = 0.f;
    __syncthreads();
    const float* xwb = xw + (size_t)b * SS * G4;
    float* hout = hseq + (size_t)b * SS * DIM;
    int p = 0;
    for (int t = 0; t < SS; ++t){
        float acc = xwb[t * G4 + g];
        const float4* h4 = (const float4*)hbuf[p];
#pragma unroll
        for (int j = 0; j < 32; ++j){
            float4 hv = h4[j];  // uniform address -> broadcast, conflict-free
            acc = fmaf(hv.x, w[j].x, fmaf(hv.y, w[j].y, fmaf(hv.z, w[j].z, fmaf(hv.w, w[j].w, acc))));
        }
        gates[g] = acc;
        __syncthreads();
        if (g < DIM){
            float iv = sigm_(gates[g]);
            float fv = sigm_(gates[DIM + g]);
            float gv = tanh_(gates[2 * DIM + g]);
            float ov = sigm_(gates[3 * DIM + g]);
            c = fv * c + iv * gv;
            float h = ov * tanh_(c);
            hbuf[p ^ 1][g] = h;
            hout[t * DIM + g] = h;
        }
        __syncthreads();
        p ^= 1;
    }
}

// ---------------- K4: LayerNorm -> bf16 ----------------
// 2048 blocks x 256 threads; one wave per row.
__global__ void k_ln(const float* __restrict__ hseq, const float* __restrict__ gamma,
                     const float* __restrict__ beta, __hip_bfloat16* __restrict__ hn){
    int wid = threadIdx.x >> 6;
    int lane = threadIdx.x & 63;
    int row = blockIdx.x * 4 + wid;
    float2 hv = ((const float2*)(hseq + (size_t)row * DIM))[lane];
    float s = hv.x + hv.y;
    float sq = fmaf(hv.x, hv.x, hv.y * hv.y);
    for (int off = 32; off; off >>= 1){ s += __shfl_xor(s, off); sq += __shfl_xor(sq, off); }
    float mu = s * (1.f / 128.f);
    float var = sq * (1.f / 128.f) - mu * mu;
    float inv = rsqrtf(var + 1e-5f);
    float2 gv = ((const float2*)gamma)[lane];
    float2 bv = ((const float2*)beta)[lane];
    __hip_bfloat162 pr;
    pr.x = __float2bfloat16((hv.x - mu) * inv * gv.x + bv.x);
    pr.y = __float2bfloat16((hv.y - mu) * inv * gv.y + bv.y);
    ((__hip_bfloat162*)hn)[(size_t)row * 64 + lane] = pr;
}

// ---------------- K5: head_W fp32 -> bf16 ----------------
__global__ void k_cvt(const float* __restrict__ w, __hip_bfloat16* __restrict__ wb){
    int i = blockIdx.x * blockDim.x + threadIdx.x;  // float4 index, 1,024,000 total
    float4 v = ((const float4*)w)[i];
    __hip_bfloat162 p0, p1;
    p0.x = __float2bfloat16(v.x); p0.y = __float2bfloat16(v.y);
    p1.x = __float2bfloat16(v.z); p1.y = __float2bfloat16(v.w);
    ((__hip_bfloat162*)wb)[2 * i]     = p0;
    ((__hip_bfloat162*)wb)[2 * i + 1] = p1;
}

// ---------------- K6: head GEMM (bf16 MFMA, K=128, no LDS) ----------------
// grid (250, 64) x 256 threads (4 waves, each owns a 64x64 quadrant of a 128x128 tile)
__global__ __launch_bounds__(256) void k_head(const __hip_bfloat16* __restrict__ hn,
                                              const __hip_bfloat16* __restrict__ wb,
                                              const float* __restrict__ head_b,
                                              float* __restrict__ out){
    int bn = blockIdx.x;          // col tile: 250 * 128 = 32000
    int bm = blockIdx.y;          // row tile: 64 * 128 = 8192
    int wid = threadIdx.x >> 6;
    int lane = threadIdx.x & 63;
    int wr = wid >> 1, wc = wid & 1;
    int row0 = bm * 128 + wr * 64;
    int col0 = bn * 128 + wc * 64;
    const short* A  = (const short*)hn;   // [8192][128] bf16 row-major
    const short* Bp = (const short*)wb;   // [32000][128] bf16 row-major (= B^T)
    f32x4 zero = {0.f, 0.f, 0.f, 0.f};
    f32x4 acc[4][4];
#pragma unroll
    for (int i = 0; i < 4; ++i)
#pragma unroll
        for (int j = 0; j < 4; ++j) acc[i][j] = zero;
    int lrow = lane & 15;
    int kgr = (lane >> 4) * 8;
#pragma unroll
    for (int ks = 0; ks < 4; ++ks){
        short8 a[4], bf[4];
#pragma unroll
        for (int mi = 0; mi < 4; ++mi)
            a[mi] = *(const short8*)(A + (size_t)(row0 + mi * 16 + lrow) * DIM + ks * 32 + kgr);
#pragma unroll
        for (int ni = 0; ni < 4; ++ni)
            bf[ni] = *(const short8*)(Bp + (size_t)(col0 + ni * 16 + lrow) * DIM + ks * 32 + kgr);
#pragma unroll
        for (int mi = 0; mi < 4; ++mi)
#pragma unroll
            for (int ni = 0; ni < 4; ++ni)
                acc[mi][ni] = __builtin_amdgcn_mfma_f32_16x16x32_bf16(a[mi], bf[ni], acc[mi][ni], 0, 0, 0);
    }
    int orow = (lane >> 4) * 4;
#pragma unroll
    for (int ni = 0; ni < 4; ++ni){
        int col = col0 + ni * 16 + lrow;
        float bias = head_b[col];
#pragma unroll
        for (int mi = 0; mi < 4; ++mi){
            size_t base = (size_t)(row0 + mi * 16 + orow) * VOCAB + col;
#pragma unroll
            for (int r = 0; r < 4; ++r)
                out[base + (size_t)r * VOCAB] = acc[mi][ni][r] + bias;
        }
    }
}

extern "C" void kernel_launch(void* const* d_in, const int* in_sizes, int n_in,
                              void* d_out, int out_size, void* d_ws, size_t ws_size,
                              hipStream_t stream){
    const int*   x     = (const int*)  d_in[0];
    const float* emb   = (const float*)d_in[1];
    const float* Wih   = (const float*)d_in[2];
    const float* Whh   = (const float*)d_in[3];
    const float* bih   = (const float*)d_in[4];
    const float* bhh   = (const float*)d_in[5];
    const float* gamma = (const float*)d_in[6];
    const float* beta  = (const float*)d_in[7];
    const float* headW = (const float*)d_in[8];
    const float* headb = (const float*)d_in[9];
    float* out = (float*)d_out;

    char* ws = (char*)d_ws;
    float* hseq = (float*)ws;                               // 4 MB  [8192][128]
    float* xw   = (float*)(ws + (4u << 20));                // 16 MB [8192][512]
    __hip_bfloat16* hn = (__hip_bfloat16*)(ws + (20u << 20)); // 2 MB
    __hip_bfloat16* wb = (__hip_bfloat16*)(ws + (22u << 20)); // 8 MB

    k_embed<<<1024, 256, 0, stream>>>(x, emb, hseq);
    k_cvt<<<4000, 256, 0, stream>>>(headW, wb);
    for (int l = 0; l < NL; ++l){
        k_xw<<<256, 512, 0, stream>>>(hseq, Wih + (size_t)l * G4 * DIM,
                                      bih + l * G4, bhh + l * G4, xw);
        k_scan<<<32, 512, 0, stream>>>(xw, Whh + (size_t)l * G4 * DIM, hseq);
    }
    k_ln<<<2048, 256, 0, stream>>>(hseq, gamma, beta, hn);
    k_head<<<dim3(250, 64), 256, 0, stream>>>(hn, wb, headb, out);
}

// Round 3
// 1347.017 us; speedup vs baseline: 1.2500x; 1.2500x over previous
//
#include <hip/hip_runtime.h>
#include <hip/hip_bf16.h>

#define DIM 128
#define G4 512      // 4*DIM
#define NL 4
#define VOCAB 32000
#define BB 32
#define SS 256
#define ROWS (BB*SS)   // 8192

typedef __attribute__((ext_vector_type(8))) short short8;
typedef __attribute__((ext_vector_type(4))) float f32x4;

__device__ __forceinline__ float fexp_(float x){ return __builtin_amdgcn_exp2f(x * 1.44269504088896f); }
__device__ __forceinline__ float frcp_(float x){ return __builtin_amdgcn_rcpf(x); }
__device__ __forceinline__ float sigm_(float x){ return frcp_(1.f + fexp_(-x)); }
__device__ __forceinline__ float tanh_(float x){
    float ax = fabsf(x);
    float e = fexp_(-2.f * ax);
    float t = (1.f - e) * frcp_(1.f + e);
    return x < 0.f ? -t : t;
}

// data accesses: relaxed agent-scope (sc1 — LLC-coherent path)
__device__ __forceinline__ void st_data(float* p, float v){
    __hip_atomic_store(p, v, __ATOMIC_RELAXED, __HIP_MEMORY_SCOPE_AGENT);
}
__device__ __forceinline__ float ld_data(const float* p){
    return __hip_atomic_load(p, __ATOMIC_RELAXED, __HIP_MEMORY_SCOPE_AGENT);
}
// flag release: makes all prior stores (drained by __syncthreads) agent-visible
__device__ __forceinline__ void rel_flag(int* p, int v){
    __hip_atomic_store(p, v, __ATOMIC_RELEASE, __HIP_MEMORY_SCOPE_AGENT);
}
// acquire spin with monotone caching: skip the LLC round-trip when the last
// observed value already covers the target (correct: flags only increase, and
// the earlier acquire synchronized-with that release).
__device__ __forceinline__ void wait_flag(const int* p, int target, int& seen){
    if (seen >= target) return;
    int v;
    do {
        v = __hip_atomic_load(p, __ATOMIC_ACQUIRE, __HIP_MEMORY_SCOPE_AGENT);
        if (v < target) __builtin_amdgcn_s_sleep(2);
    } while (v < target);
    seen = v;
}

// ---------------- K0: zero the pipeline flags ----------------
__global__ void k_zero(int* __restrict__ f){ f[threadIdx.x] = 0; }

// ---------------- K1: embedding gather ----------------
__global__ void k_embed(const int* __restrict__ x, const float* __restrict__ emb,
                        float* __restrict__ hseq){
    int i = blockIdx.x * blockDim.x + threadIdx.x;
    int row = i >> 5;
    int d4  = i & 31;
    int tok = x[row];
    ((float4*)hseq)[i] = ((const float4*)emb)[tok * 32 + d4];
}

// ---------------- K2: xw0 = hseq0 @ Wih0^T + b (layer 0 only) ----------------
__global__ __launch_bounds__(512, 2) void k_xw(const float* __restrict__ hseq,
                                               const float* __restrict__ Wih,
                                               const float* __restrict__ bih,
                                               const float* __restrict__ bhh,
                                               float* __restrict__ xw){
    __shared__ float hs[32 * DIM];
    int g = threadIdx.x;
    int r0 = blockIdx.x * 32;
    {
        const float4* src = (const float4*)(hseq + (size_t)r0 * DIM);
        float4* dst = (float4*)hs;
        for (int j = g; j < 32 * 32; j += 512) dst[j] = src[j];
    }
    float4 w[32];
    const float4* wr = (const float4*)(Wih + (size_t)g * DIM);
#pragma unroll
    for (int j = 0; j < 32; ++j) w[j] = wr[j];
    float bias = bih[g] + bhh[g];
    __syncthreads();
    for (int r = 0; r < 32; ++r){
        const float4* h4 = (const float4*)(hs + r * DIM);
        float acc = bias;
#pragma unroll
        for (int j = 0; j < 32; ++j){
            float4 hv = h4[j];
            acc = fmaf(hv.x, w[j].x, fmaf(hv.y, w[j].y, fmaf(hv.z, w[j].z, fmaf(hv.w, w[j].w, acc))));
        }
        xw[(size_t)(r0 + r) * G4 + g] = acc;
    }
}

// ---------------- K3: pipelined 4-layer LSTM scan ----------------
// 224 blocks x 512 threads, all co-resident (224 <= 256 CUs even at 1 block/CU).
// Blocks 0..127  : scan block (layer l = bid>>5, batch b = bid&31)
// Blocks 128..223: xw producer for layers 1..3
// Handoff protocol: data stores -> __syncthreads (vmcnt drain) -> RELEASE flag;
// consumer: ACQUIRE spin (one thread, monotone-cached) -> __syncthreads -> loads.
__global__ __launch_bounds__(512, 2) void k_pipe(
    const float* __restrict__ xw0,
    const float* __restrict__ Wih, const float* __restrict__ Whh,
    const float* __restrict__ bih, const float* __restrict__ bhh,
    float* __restrict__ hstream, float* __restrict__ xws,
    int* __restrict__ flags)
{
    const int g = threadIdx.x;
    const int bid = blockIdx.x;
    int* hflag  = flags;        // [4][32]
    int* xwflag = flags + 128;  // [3][32]

    if (bid < 128){
        // ---- scan block ----
        const int l = bid >> 5, b = bid & 31;
        __shared__ float hbuf[2][DIM];
        __shared__ float gates[G4];
        float4 w[32];
        {
            const float4* wr = (const float4*)(Whh + ((size_t)l * G4 + g) * DIM);
#pragma unroll
            for (int j = 0; j < 32; ++j) w[j] = wr[j];
        }
        const float* xwsrc = (l == 0) ? (xw0 + (size_t)b * SS * G4)
                                      : (xws + (size_t)((l - 1) * 32 + b) * SS * G4);
        int* inflag  = (l == 0) ? nullptr : (xwflag + (l - 1) * 32 + b);
        float* hout  = hstream + (size_t)(l * 32 + b) * SS * DIM;
        int* outflag = hflag + l * 32 + b;
        float c = 0.f;
        int seen = 0;
        if (g < DIM) hbuf[0][g] = 0.f;

        if (l > 0 && g == 0) wait_flag(inflag, 1, seen);
        __syncthreads();
        float r = (l == 0) ? xwsrc[g] : ld_data(xwsrc + g);
        int p = 0;
        for (int t = 0; t < SS; ++t){
            float a0 = 0.f, a1 = 0.f, a2 = 0.f, a3 = 0.f;
            const float4* h4 = (const float4*)hbuf[p];
#pragma unroll
            for (int j = 0; j < 32; j += 4){
                float4 v0 = h4[j], v1 = h4[j+1], v2 = h4[j+2], v3 = h4[j+3];
                a0 = fmaf(v0.x, w[j  ].x, fmaf(v0.y, w[j  ].y, fmaf(v0.z, w[j  ].z, fmaf(v0.w, w[j  ].w, a0))));
                a1 = fmaf(v1.x, w[j+1].x, fmaf(v1.y, w[j+1].y, fmaf(v1.z, w[j+1].z, fmaf(v1.w, w[j+1].w, a1))));
                a2 = fmaf(v2.x, w[j+2].x, fmaf(v2.y, w[j+2].y, fmaf(v2.z, w[j+2].z, fmaf(v2.w, w[j+2].w, a2))));
                a3 = fmaf(v3.x, w[j+3].x, fmaf(v3.y, w[j+3].y, fmaf(v3.z, w[j+3].z, fmaf(v3.w, w[j+3].w, a3))));
            }
            gates[g] = r + (a0 + a1) + (a2 + a3);
            // acquire xw_{t+1} availability before the barrier (usually cached, no load)
            if (l > 0 && g == 0 && t + 1 < SS) wait_flag(inflag, t + 2, seen);
            __syncthreads();
            float rn = 0.f;
            if (t + 1 < SS)
                rn = (l == 0) ? xwsrc[(size_t)(t + 1) * G4 + g]
                              : ld_data(xwsrc + (size_t)(t + 1) * G4 + g);
            if (g < DIM){
                float iv = sigm_(gates[g]);
                float fv = sigm_(gates[DIM + g]);
                float gv = tanh_(gates[2 * DIM + g]);
                float ov = sigm_(gates[3 * DIM + g]);
                c = fv * c + iv * gv;
                float h = ov * tanh_(c);
                hbuf[p ^ 1][g] = h;
                st_data(hout + (size_t)t * DIM + g, h);
            }
            __syncthreads();                      // drains every wave's h stores
            if (g == 0) rel_flag(outflag, t + 1); // release: wb L2 + sc1 store
            r = rn; p ^= 1;
        }
    } else {
        // ---- xw producer block (layers 1..3) ----
        const int jj = bid - 128;
        const int l = 1 + (jj >> 5), b = jj & 31;
        __shared__ float hstage[2][DIM];
        float4 w[32];
        {
            const float4* wr = (const float4*)(Wih + ((size_t)l * G4 + g) * DIM);
#pragma unroll
            for (int j = 0; j < 32; ++j) w[j] = wr[j];
        }
        const float bias = bih[l * G4 + g] + bhh[l * G4 + g];
        const float* hsrc = hstream + (size_t)((l - 1) * 32 + b) * SS * DIM;
        int* inflag  = hflag + (l - 1) * 32 + b;
        float* xwdst = xws + (size_t)((l - 1) * 32 + b) * SS * G4;
        int* outflag = xwflag + (l - 1) * 32 + b;
        int seen = 0;

        // startup: hstage[0] = h_0 ; nregs = h_1
        if (g == 0) wait_flag(inflag, 1, seen);
        __syncthreads();
        if (g < 32){
            const float* s = hsrc + g * 4;
            hstage[0][g*4+0] = ld_data(s+0); hstage[0][g*4+1] = ld_data(s+1);
            hstage[0][g*4+2] = ld_data(s+2); hstage[0][g*4+3] = ld_data(s+3);
        }
        if (g == 0) wait_flag(inflag, 2, seen);
        __syncthreads();
        float n0 = 0.f, n1 = 0.f, n2 = 0.f, n3 = 0.f;
        if (g < 32){
            const float* s = hsrc + DIM + g * 4;
            n0 = ld_data(s+0); n1 = ld_data(s+1); n2 = ld_data(s+2); n3 = ld_data(s+3);
        }
        for (int t = 0; t < SS; ++t){
            float a0 = bias, a1 = 0.f, a2 = 0.f, a3 = 0.f;
            const float4* h4 = (const float4*)hstage[t & 1];
#pragma unroll
            for (int j = 0; j < 32; j += 4){
                float4 v0 = h4[j], v1 = h4[j+1], v2 = h4[j+2], v3 = h4[j+3];
                a0 = fmaf(v0.x, w[j  ].x, fmaf(v0.y, w[j  ].y, fmaf(v0.z, w[j  ].z, fmaf(v0.w, w[j  ].w, a0))));
                a1 = fmaf(v1.x, w[j+1].x, fmaf(v1.y, w[j+1].y, fmaf(v1.z, w[j+1].z, fmaf(v1.w, w[j+1].w, a1))));
                a2 = fmaf(v2.x, w[j+2].x, fmaf(v2.y, w[j+2].y, fmaf(v2.z, w[j+2].z, fmaf(v2.w, w[j+2].w, a2))));
                a3 = fmaf(v3.x, w[j+3].x, fmaf(v3.y, w[j+3].y, fmaf(v3.z, w[j+3].z, fmaf(v3.w, w[j+3].w, a3))));
            }
            st_data(xwdst + (size_t)t * G4 + g, (a0 + a1) + (a2 + a3));
            // acquire availability of h_{t+2} (usually cached, no load)
            if (g == 0 && t + 2 < SS) wait_flag(inflag, t + 3, seen);
            __syncthreads();
            if (g < 32){
                if (t + 1 < SS){   // commit h_{t+1} (prefetched last step) to LDS
                    hstage[(t+1)&1][g*4+0] = n0; hstage[(t+1)&1][g*4+1] = n1;
                    hstage[(t+1)&1][g*4+2] = n2; hstage[(t+1)&1][g*4+3] = n3;
                }
                if (t + 2 < SS){   // issue load of h_{t+2}; full step to complete
                    const float* s = hsrc + (size_t)(t + 2) * DIM + g * 4;
                    n0 = ld_data(s+0); n1 = ld_data(s+1); n2 = ld_data(s+2); n3 = ld_data(s+3);
                }
            }
            __syncthreads();                      // drains xw stores (and LDS)
            if (g == 0) rel_flag(outflag, t + 1);
        }
    }
}

// ---------------- K4: LayerNorm -> bf16 ----------------
__global__ void k_ln(const float* __restrict__ hseq, const float* __restrict__ gamma,
                     const float* __restrict__ beta, __hip_bfloat16* __restrict__ hn){
    int wid = threadIdx.x >> 6;
    int lane = threadIdx.x & 63;
    int row = blockIdx.x * 4 + wid;
    float2 hv = ((const float2*)(hseq + (size_t)row * DIM))[lane];
    float s = hv.x + hv.y;
    float sq = fmaf(hv.x, hv.x, hv.y * hv.y);
    for (int off = 32; off; off >>= 1){ s += __shfl_xor(s, off); sq += __shfl_xor(sq, off); }
    float mu = s * (1.f / 128.f);
    float var = sq * (1.f / 128.f) - mu * mu;
    float inv = rsqrtf(var + 1e-5f);
    float2 gv = ((const float2*)gamma)[lane];
    float2 bv = ((const float2*)beta)[lane];
    __hip_bfloat162 pr;
    pr.x = __float2bfloat16((hv.x - mu) * inv * gv.x + bv.x);
    pr.y = __float2bfloat16((hv.y - mu) * inv * gv.y + bv.y);
    ((__hip_bfloat162*)hn)[(size_t)row * 64 + lane] = pr;
}

// ---------------- K5: head_W fp32 -> bf16 ----------------
__global__ void k_cvt(const float* __restrict__ w, __hip_bfloat16* __restrict__ wb){
    int i = blockIdx.x * blockDim.x + threadIdx.x;
    float4 v = ((const float4*)w)[i];
    __hip_bfloat162 p0, p1;
    p0.x = __float2bfloat16(v.x); p0.y = __float2bfloat16(v.y);
    p1.x = __float2bfloat16(v.z); p1.y = __float2bfloat16(v.w);
    ((__hip_bfloat162*)wb)[2 * i]     = p0;
    ((__hip_bfloat162*)wb)[2 * i + 1] = p1;
}

// ---------------- K6: head GEMM (bf16 MFMA, swapped operands, float4 stores) ----
// D = mfma(A=wb_frag, B=hn_frag): first-arg dim -> (lane>>4)*4+reg (out COL),
// second-arg dim -> lane&15 (out ROW). Each lane owns 4 consecutive cols per
// (mi,ni) -> global_store_dwordx4, L2 merges 64B halves into full lines.
__global__ __launch_bounds__(256) void k_head(const __hip_bfloat16* __restrict__ hn,
                                              const __hip_bfloat16* __restrict__ wb,
                                              const float* __restrict__ head_b,
                                              float* __restrict__ out){
    int bn = blockIdx.x;
    int bm = blockIdx.y;
    int wid = threadIdx.x >> 6;
    int lane = threadIdx.x & 63;
    int wr = wid >> 1, wc = wid & 1;
    int row0 = bm * 128 + wr * 64;
    int col0 = bn * 128 + wc * 64;
    const short* A  = (const short*)hn;   // [8192][128]
    const short* Bp = (const short*)wb;   // [32000][128]
    f32x4 zero = {0.f, 0.f, 0.f, 0.f};
    f32x4 acc[4][4];   // [mi][ni]
#pragma unroll
    for (int i = 0; i < 4; ++i)
#pragma unroll
        for (int j = 0; j < 4; ++j) acc[i][j] = zero;
    int lrow = lane & 15;
    int kgr = (lane >> 4) * 8;
#pragma unroll
    for (int ks = 0; ks < 4; ++ks){
        short8 a[4], bf[4];
#pragma unroll
        for (int mi = 0; mi < 4; ++mi)
            a[mi] = *(const short8*)(A + (size_t)(row0 + mi * 16 + lrow) * DIM + ks * 32 + kgr);
#pragma unroll
        for (int ni = 0; ni < 4; ++ni)
            bf[ni] = *(const short8*)(Bp + (size_t)(col0 + ni * 16 + lrow) * DIM + ks * 32 + kgr);
#pragma unroll
        for (int mi = 0; mi < 4; ++mi)
#pragma unroll
            for (int ni = 0; ni < 4; ++ni)
                acc[mi][ni] = __builtin_amdgcn_mfma_f32_16x16x32_bf16(bf[ni], a[mi], acc[mi][ni], 0, 0, 0);
    }
    int csub = (lane >> 4) * 4;   // col offset within 16
#pragma unroll
    for (int ni = 0; ni < 4; ++ni){
        int cbase = col0 + ni * 16 + csub;
        float4 b4 = ((const float4*)head_b)[cbase >> 2];
#pragma unroll
        for (int mi = 0; mi < 4; ++mi){
            int row = row0 + mi * 16 + lrow;
            float4 v;
            v.x = acc[mi][ni][0] + b4.x;
            v.y = acc[mi][ni][1] + b4.y;
            v.z = acc[mi][ni][2] + b4.z;
            v.w = acc[mi][ni][3] + b4.w;
            *(float4*)(out + (size_t)row * VOCAB + cbase) = v;
        }
    }
}

extern "C" void kernel_launch(void* const* d_in, const int* in_sizes, int n_in,
                              void* d_out, int out_size, void* d_ws, size_t ws_size,
                              hipStream_t stream){
    const int*   x     = (const int*)  d_in[0];
    const float* emb   = (const float*)d_in[1];
    const float* Wih   = (const float*)d_in[2];
    const float* Whh   = (const float*)d_in[3];
    const float* bih   = (const float*)d_in[4];
    const float* bhh   = (const float*)d_in[5];
    const float* gamma = (const float*)d_in[6];
    const float* beta  = (const float*)d_in[7];
    const float* headW = (const float*)d_in[8];
    const float* headb = (const float*)d_in[9];
    float* out = (float*)d_out;

    char* ws = (char*)d_ws;
    float* xw0   = (float*)ws;                                 // 16 MB [8192][512]
    float* hseq0 = (float*)(ws + (16u << 20));                 // 4 MB  [8192][128]
    __hip_bfloat16* hn = (__hip_bfloat16*)(ws + (20u << 20));  // 2 MB
    __hip_bfloat16* wb = (__hip_bfloat16*)(ws + (22u << 20));  // 8 MB

    // pipeline streams in the FRONT of d_out; k_head fully overwrites d_out after.
    char* ob = (char*)d_out;
    float* hstream = (float*)ob;                    // 16 MB [4][32][256][128]
    float* xws     = (float*)(ob + (16u << 20));    // 48 MB [3][32][256][512]
    int*   flags   = (int*)  (ob + (64u << 20));    // 256 ints

    k_zero <<<1, 256, 0, stream>>>(flags);
    k_embed<<<1024, 256, 0, stream>>>(x, emb, hseq0);
    k_cvt  <<<4000, 256, 0, stream>>>(headW, wb);
    k_xw   <<<256, 512, 0, stream>>>(hseq0, Wih, bih, bhh, xw0);
    k_pipe <<<224, 512, 0, stream>>>(xw0, Wih, Whh, bih, bhh, hstream, xws, flags);
    k_ln   <<<2048, 256, 0, stream>>>(hstream + (size_t)3 * 32 * SS * DIM, gamma, beta, hn);
    k_head <<<dim3(250, 64), 256, 0, stream>>>(hn, wb, headb, out);
}